// Round 3
// baseline (1096.840 us; speedup 1.0000x reference)
//
#include <hip/hip_runtime.h>
#include <hip/hip_bf16.h>
#include <math.h>

// SlotAttention: B=64 N=4096 F=256 D=256 KVQ=256 H=4 S=8 DH=64 ITERS=3
// Round 3: all-direct MFMA GEMM (no operand LDS, LN affine epilogue, V stored
// transposed), MFMA attention (wave=head), 4-way-split GRU.

using frag_ab = __attribute__((ext_vector_type(8))) short;   // 8 bf16
using f32x4  = __attribute__((ext_vector_type(4))) float;

__device__ __forceinline__ unsigned short f2bf(float f) {
  unsigned int x = __float_as_uint(f);
  x += 0x7fffu + ((x >> 16) & 1u);   // RNE
  return (unsigned short)(x >> 16);
}
__device__ __forceinline__ float bf2f(unsigned short u) {
  return __uint_as_float((unsigned int)u << 16);
}

// ---------------------------------------------------------------------------
// Weight prep: Wp[n][k] = bf16(W[n][k]*lnw[k]); c12[n]=sum(b*W), c12[512+n]=sum(w*W)
__global__ __launch_bounds__(256) void k_wprep(
    const float* __restrict__ wk, const float* __restrict__ wv,
    const float* __restrict__ lnw, const float* __restrict__ lnb,
    unsigned short* __restrict__ Wp, float* __restrict__ c12) {
  const int lane = threadIdx.x & 63;
  const int n = blockIdx.x * 4 + (threadIdx.x >> 6);
  const float* W = (n < 256) ? (wk + n * 256) : (wv + (long)(n - 256) * 256);
  const float4 w4 = *(const float4*)(W + lane * 4);
  const float4 g4 = *(const float4*)(lnw + lane * 4);
  const float4 b4 = *(const float4*)(lnb + lane * 4);
  float c1 = w4.x * b4.x + w4.y * b4.y + w4.z * b4.z + w4.w * b4.w;
  float c2 = w4.x * g4.x + w4.y * g4.y + w4.z * g4.z + w4.w * g4.w;
  uint2 o;
  o.x = (unsigned)f2bf(w4.x * g4.x) | ((unsigned)f2bf(w4.y * g4.y) << 16);
  o.y = (unsigned)f2bf(w4.z * g4.z) | ((unsigned)f2bf(w4.w * g4.w) << 16);
  *(uint2*)(Wp + n * 256 + lane * 4) = o;
#pragma unroll
  for (int m = 1; m < 64; m <<= 1) {
    c1 += __shfl_xor(c1, m);
    c2 += __shfl_xor(c2, m);
  }
  if (lane == 0) {
    c12[n] = c1;
    c12[512 + n] = c2;
  }
}

// ---------------------------------------------------------------------------
__global__ void k_transpose(const float* __restrict__ wih,
                            const float* __restrict__ whh,
                            const float* __restrict__ wqs,
                            float* __restrict__ wihT, float* __restrict__ whhT,
                            float* __restrict__ wqT) {
  const int idx = blockIdx.x * 256 + threadIdx.x;
  if (idx < 768 * 256) {
    const int g = idx >> 8, k = idx & 255;
    wihT[k * 768 + g] = wih[idx];
  } else if (idx < 2 * 768 * 256) {
    const int j = idx - 768 * 256;
    const int g = j >> 8, k = j & 255;
    whhT[k * 768 + g] = whh[j];
  } else {
    const int j = idx - 2 * 768 * 256;
    const int c = j >> 8, k = j & 255;
    wqT[k * 256 + c] = wqs[j];
  }
}

// ---------------------------------------------------------------------------
// Projection GEMM, all-direct: BM=32, BN=512 (full N), K=256. 4 waves, wave w
// covers cols w*128..+127. A fp32 read once (stats accumulated in-flight),
// B (Wp, 256KB) from L2 straight to regs. Epilogue: LN affine; K row-major,
// V transposed to Vt[b][d][j].
__global__ __launch_bounds__(256) void k_gemm(
    const float* __restrict__ xin, const unsigned short* __restrict__ Wp,
    const float* __restrict__ c12, unsigned short* __restrict__ Kb,
    unsigned short* __restrict__ Vt) {
  __shared__ __align__(16) char sh[16384 + 18432];  // K repack | V repack(256*72)
  const int t = threadIdx.x;
  const int lane = t & 63, w = t >> 6;
  const int li = lane & 15;     // A-row-within-16 / B-col-within-16
  const int kg = lane >> 4;     // k-subgroup
  const long row0 = (long)blockIdx.x * 32;

  f32x4 acc[2][8];
#pragma unroll
  for (int m = 0; m < 2; ++m)
#pragma unroll
    for (int n = 0; n < 8; ++n) acc[m][n] = (f32x4){0.f, 0.f, 0.f, 0.f};

  float s0 = 0.f, ss0 = 0.f, s1 = 0.f, ss1 = 0.f;

  for (int ks = 0; ks < 4; ++ks) {
    frag_ab af[2][2];
#pragma unroll
    for (int m = 0; m < 2; ++m)
#pragma unroll
    for (int kk = 0; kk < 2; ++kk) {
      const float4* ap = (const float4*)(xin + (row0 + m * 16 + li) * 256 +
                                         ks * 64 + kk * 32 + kg * 8);
      const float4 a0 = ap[0];
      const float4 a1 = ap[1];
      const float sl = a0.x + a0.y + a0.z + a0.w + a1.x + a1.y + a1.z + a1.w;
      const float ssl = a0.x * a0.x + a0.y * a0.y + a0.z * a0.z + a0.w * a0.w +
                        a1.x * a1.x + a1.y * a1.y + a1.z * a1.z + a1.w * a1.w;
      if (m == 0) { s0 += sl; ss0 += ssl; } else { s1 += sl; ss1 += ssl; }
      union { frag_ab f; unsigned short u[8]; } tp;
      tp.u[0] = f2bf(a0.x); tp.u[1] = f2bf(a0.y);
      tp.u[2] = f2bf(a0.z); tp.u[3] = f2bf(a0.w);
      tp.u[4] = f2bf(a1.x); tp.u[5] = f2bf(a1.y);
      tp.u[6] = f2bf(a1.z); tp.u[7] = f2bf(a1.w);
      af[m][kk] = tp.f;
    }
#pragma unroll
    for (int kk = 0; kk < 2; ++kk)
#pragma unroll
      for (int n = 0; n < 8; ++n) {
        const int col = w * 128 + n * 16 + li;
        const frag_ab bf =
            *(const frag_ab*)(Wp + (long)col * 256 + ks * 64 + kk * 32 + kg * 8);
        acc[0][n] = __builtin_amdgcn_mfma_f32_16x16x32_bf16(af[0][kk], bf, acc[0][n], 0, 0, 0);
        acc[1][n] = __builtin_amdgcn_mfma_f32_16x16x32_bf16(af[1][kk], bf, acc[1][n], 0, 0, 0);
      }
  }
  // stats: reduce over kg lanes; then all lanes hold sums for row m*16+li
  s0 += __shfl_xor(s0, 16); s0 += __shfl_xor(s0, 32);
  ss0 += __shfl_xor(ss0, 16); ss0 += __shfl_xor(ss0, 32);
  s1 += __shfl_xor(s1, 16); s1 += __shfl_xor(s1, 32);
  ss1 += __shfl_xor(ss1, 16); ss1 += __shfl_xor(ss1, 32);
  const float mn0 = s0 * (1.f / 256.f);
  const float rst0 = rsqrtf(ss0 * (1.f / 256.f) - mn0 * mn0 + 1e-5f);
  const float mn1 = s1 * (1.f / 256.f);
  const float rst1 = rsqrtf(ss1 * (1.f / 256.f) - mn1 * mn1 + 1e-5f);

  // epilogue: affine + repack
  unsigned short* Krep = (unsigned short*)sh;       // [32][256] swizzled rows
  unsigned short* Vrep = (unsigned short*)(sh + 16384);  // [256 d][stride 36] j
#pragma unroll
  for (int m = 0; m < 2; ++m) {
#pragma unroll
    for (int r = 0; r < 4; ++r) {
      const int row = m * 16 + kg * 4 + r;
      const int src = kg * 4 + r;
      const float mnv = __shfl(m == 0 ? mn0 : mn1, src);
      const float rsv = __shfl(m == 0 ? rst0 : rst1, src);
#pragma unroll
      for (int n = 0; n < 8; ++n) {
        const int col = w * 128 + n * 16 + li;
        const float val =
            rsv * acc[m][n][r] + (c12[col] - mnv * rsv * c12[512 + col]);
        const unsigned short bv = f2bf(val);
        if (w < 2) {  // K half: Krep[row][col], row-xor swizzle
          const int off = (row * 512 + col * 2) ^ (((row >> 2) & 3) << 5);
          *(unsigned short*)((char*)Krep + off) = bv;
        } else {      // V half: Vrep[d][j=row], stride 72B
          const int d = col - 256;
          *(unsigned short*)((char*)Vrep + d * 72 + row * 2) = bv;
        }
      }
    }
  }
  __syncthreads();
  // K store: rows (row0+row) of Kb
#pragma unroll
  for (int p = 0; p < 4; ++p) {
    const int idx = p * 256 + t;
    const int row = idx >> 5;
    const int coff = (idx & 31) * 16;
    const uint4 v = *(const uint4*)((char*)Krep +
                                    ((row * 512 + coff) ^ (((row >> 2) & 3) << 5)));
    *(uint4*)(Kb + (row0 + row) * 256 + coff / 2) = v;
  }
  // V store: Vt[b*256+d][4096 j]
  const long b = row0 >> 12;
  const long jb = row0 & 4095;
#pragma unroll
  for (int p = 0; p < 4; ++p) {
    const int idx = p * 256 + t;
    const int d = idx >> 2;
    const int jslot = idx & 3;
    const uint4 v = *(const uint4*)((char*)Vrep + d * 72 + jslot * 16);
    *(uint4*)(Vt + (b * 256 + d) * 4096 + jb + jslot * 8) = v;
  }
}

// ---------------------------------------------------------------------------
// LN(slots) + q = sn @ wq^T. One block per b.
__global__ __launch_bounds__(256) void k_q(
    const float* __restrict__ slots, const float* __restrict__ lnw,
    const float* __restrict__ lnb, const float* __restrict__ wqT,
    float* __restrict__ qout) {
  __shared__ float sl[8 * 256];
  __shared__ float mstat[8], rstat[8];
  const int b = blockIdx.x, t = threadIdx.x;
#pragma unroll
  for (int i = 0; i < 8; ++i) sl[i * 256 + t] = slots[b * 2048 + i * 256 + t];
  __syncthreads();
  if (t < 8) {
    float s = 0.f, ss = 0.f;
    for (int k = 0; k < 256; ++k) {
      const float x = sl[t * 256 + k];
      s += x;
      ss += x * x;
    }
    const float m = s * (1.f / 256.f);
    mstat[t] = m;
    rstat[t] = rsqrtf(ss * (1.f / 256.f) - m * m + 1e-5f);
  }
  __syncthreads();
  const float w = lnw[t], bb = lnb[t];
#pragma unroll
  for (int i = 0; i < 8; ++i)
    sl[i * 256 + t] = (sl[i * 256 + t] - mstat[i]) * rstat[i] * w + bb;
  __syncthreads();
  float acc[8] = {};
  for (int k = 0; k < 256; k += 4) {
    const float w0 = wqT[(k + 0) * 256 + t];
    const float w1 = wqT[(k + 1) * 256 + t];
    const float w2 = wqT[(k + 2) * 256 + t];
    const float w3 = wqT[(k + 3) * 256 + t];
#pragma unroll
    for (int i = 0; i < 8; ++i) {
      const float4 x4 = *(const float4*)(sl + i * 256 + k);
      acc[i] += x4.x * w0 + x4.y * w1 + x4.z * w2 + x4.w * w3;
    }
  }
#pragma unroll
  for (int i = 0; i < 8; ++i) qout[b * 2048 + i * 256 + t] = acc[i];
}

// ---------------------------------------------------------------------------
// MFMA attention: block (jt,b) does 256 j in 8 chunks of 32. Wave = head h.
// QK^T: A=K rows (direct global), B=Q frag (built once). Softmax over 32
// (i,h) per j. PV: A=P (from dsm), B=V^T (direct global, j-contiguous).
template <bool LAST>
__global__ __launch_bounds__(256) void k_att(
    const float* __restrict__ qin, const unsigned short* __restrict__ Kb,
    const unsigned short* __restrict__ Vt, float* __restrict__ upart,
    float* __restrict__ svpart, float* __restrict__ rowsum_part,
    float* __restrict__ attn_out) {
  __shared__ float dsm[32 * 33];
  __shared__ float wred[4 * 32];
  const int t = threadIdx.x;
  const int lane = t & 63;
  const int h = t >> 6;
  const int jt = blockIdx.x;
  const int b = blockIdx.y;
  const long j0 = (long)jt * 256;
  const int li = lane & 15;
  const int kg = lane >> 4;
  const bool ival = li < 8;

  // Q fragments: col=i=li (0..7 valid), k=d = ksub*32 + kg*8 + e
  frag_ab qf[2];
#pragma unroll
  for (int ksub = 0; ksub < 2; ++ksub) {
    union { frag_ab f; unsigned short u[8]; } tq;
#pragma unroll
    for (int e = 0; e < 8; ++e)
      tq.u[e] = ival ? f2bf(qin[b * 2048 + li * 256 + h * 64 + ksub * 32 + kg * 8 + e])
                     : (unsigned short)0;
    qf[ksub] = tq.f;
  }

  const int sc = t >> 3, sp = t & 7;
  float rs0 = 0, rs1 = 0, rs2 = 0, rs3 = 0;
  f32x4 pv[4];
#pragma unroll
  for (int d = 0; d < 4; ++d) pv[d] = (f32x4){0.f, 0.f, 0.f, 0.f};
  float sv[4] = {0.f, 0.f, 0.f, 0.f};

  for (int ch = 0; ch < 8; ++ch) {
    const long jc = j0 + ch * 32;
    // QK^T
    f32x4 dacc[2];
    dacc[0] = (f32x4){0.f, 0.f, 0.f, 0.f};
    dacc[1] = (f32x4){0.f, 0.f, 0.f, 0.f};
#pragma unroll
    for (int jsub = 0; jsub < 2; ++jsub)
#pragma unroll
      for (int ksub = 0; ksub < 2; ++ksub) {
        const frag_ab af =
            *(const frag_ab*)(Kb + ((long)b * 4096 + jc + jsub * 16 + li) * 256 +
                              h * 64 + ksub * 32 + kg * 8);
        dacc[jsub] = __builtin_amdgcn_mfma_f32_16x16x32_bf16(af, qf[ksub], dacc[jsub], 0, 0, 0);
      }
    __syncthreads();  // prev chunk's dsm readers done
    if (ival) {
#pragma unroll
      for (int jsub = 0; jsub < 2; ++jsub)
#pragma unroll
        for (int r = 0; r < 4; ++r)
          dsm[(jsub * 16 + kg * 4 + r) * 33 + li * 4 + h] = dacc[jsub][r] * 0.125f;
    }
    __syncthreads();
    // inverted softmax: col sc (j), 8 threads -> wait, sp=i owns 4 h vals
    {
      float v0 = dsm[sc * 33 + sp * 4 + 0];
      float v1 = dsm[sc * 33 + sp * 4 + 1];
      float v2 = dsm[sc * 33 + sp * 4 + 2];
      float v3 = dsm[sc * 33 + sp * 4 + 3];
      float mx = fmaxf(fmaxf(v0, v1), fmaxf(v2, v3));
      mx = fmaxf(mx, __shfl_xor(mx, 1));
      mx = fmaxf(mx, __shfl_xor(mx, 2));
      mx = fmaxf(mx, __shfl_xor(mx, 4));
      v0 = __expf(v0 - mx); v1 = __expf(v1 - mx);
      v2 = __expf(v2 - mx); v3 = __expf(v3 - mx);
      float sum = v0 + v1 + v2 + v3;
      sum += __shfl_xor(sum, 1);
      sum += __shfl_xor(sum, 2);
      sum += __shfl_xor(sum, 4);
      const float inv = 1.f / sum;
      v0 *= inv; v1 *= inv; v2 *= inv; v3 *= inv;
      dsm[sc * 33 + sp * 4 + 0] = v0;
      dsm[sc * 33 + sp * 4 + 1] = v1;
      dsm[sc * 33 + sp * 4 + 2] = v2;
      dsm[sc * 33 + sp * 4 + 3] = v3;
      rs0 += v0; rs1 += v1; rs2 += v2; rs3 += v3;
      if (LAST)
        attn_out[((long)(b * 8 + sp)) * 4096 + jc + sc] =
            (v0 + v1 + v2 + v3) * 0.25f;
    }
    __syncthreads();
    // PV
    frag_ab pa;
    {
      union { frag_ab f; unsigned short u[8]; } tp;
#pragma unroll
      for (int e = 0; e < 8; ++e)
        tp.u[e] = ival ? f2bf(dsm[(kg * 8 + e) * 33 + li * 4 + h]) : (unsigned short)0;
      pa = tp.f;
    }
#pragma unroll
    for (int dt = 0; dt < 4; ++dt) {
      const frag_ab vf =
          *(const frag_ab*)(Vt + ((long)b * 256 + h * 64 + dt * 16 + li) * 4096 +
                            jc + kg * 8);
      pv[dt] = __builtin_amdgcn_mfma_f32_16x16x32_bf16(pa, vf, pv[dt], 0, 0, 0);
      const unsigned short* vu = (const unsigned short*)&vf;
      float svl = 0.f;
#pragma unroll
      for (int e = 0; e < 8; ++e) svl += bf2f(vu[e]);
      sv[dt] += svl;
    }
  }
  // upart: lanes kg<2 hold i = kg*4+r
  if (kg < 2) {
#pragma unroll
    for (int dt = 0; dt < 4; ++dt)
#pragma unroll
      for (int r = 0; r < 4; ++r)
        upart[(((long)(jt * 64 + b)) * 8 + kg * 4 + r) * 256 + h * 64 + dt * 16 + li] =
            pv[dt][r];
  }
  // sv reduce across kg
#pragma unroll
  for (int dt = 0; dt < 4; ++dt) {
    sv[dt] += __shfl_xor(sv[dt], 16);
    sv[dt] += __shfl_xor(sv[dt], 32);
  }
  if (kg == 0) {
#pragma unroll
    for (int dt = 0; dt < 4; ++dt)
      svpart[((long)(jt * 64 + b)) * 256 + h * 64 + dt * 16 + li] = sv[dt];
  }
  // rowsum partials
  rs0 += __shfl_xor(rs0, 8); rs0 += __shfl_xor(rs0, 16); rs0 += __shfl_xor(rs0, 32);
  rs1 += __shfl_xor(rs1, 8); rs1 += __shfl_xor(rs1, 16); rs1 += __shfl_xor(rs1, 32);
  rs2 += __shfl_xor(rs2, 8); rs2 += __shfl_xor(rs2, 16); rs2 += __shfl_xor(rs2, 32);
  rs3 += __shfl_xor(rs3, 8); rs3 += __shfl_xor(rs3, 16); rs3 += __shfl_xor(rs3, 32);
  if ((t & 63) < 8) {
    float* wr = wred + (t >> 6) * 32 + sp * 4;
    wr[0] = rs0; wr[1] = rs1; wr[2] = rs2; wr[3] = rs3;
  }
  __syncthreads();
  if (t < 32)
    rowsum_part[((long)(jt * 64 + b)) * 32 + t] =
        wred[t] + wred[32 + t] + wred[64 + t] + wred[96 + t];
}

// ---------------------------------------------------------------------------
// GRU cell, grid (4 s, 64 b): block covers 64 output cols per gate.
template <bool LAST>
__global__ __launch_bounds__(256) void k_gru(
    const float* __restrict__ upart, const float* __restrict__ svpart,
    const float* __restrict__ rowsum_part, const float* __restrict__ wihT,
    const float* __restrict__ whhT, const float* __restrict__ bih,
    const float* __restrict__ bhh, float* __restrict__ slots,
    float* __restrict__ dout) {
  __shared__ float xl[8 * 256];
  __shared__ float hl[8 * 256];
  __shared__ float rs[32];
  __shared__ float gbuf[3 * 1024];  // [gate][{gi,gh}][8 r][64 c]
  const int t = threadIdx.x;
  const int s = blockIdx.x;
  const int b = blockIdx.y;
  if (t < 32) {
    float s2 = 0.f;
#pragma unroll
    for (int p = 0; p < 16; ++p) s2 += rowsum_part[((long)(p * 64 + b)) * 32 + t];
    rs[t] = 1.f / (s2 + 4096.f * 1e-8f);
  }
  float svs = 0.f;
#pragma unroll
  for (int p = 0; p < 16; ++p) svs += svpart[((long)(p * 64 + b)) * 256 + t];
  __syncthreads();
  const int hcol = t >> 6;
#pragma unroll
  for (int r = 0; r < 8; ++r) {
    float pp = 0.f;
#pragma unroll
    for (int p = 0; p < 16; ++p)
      pp += upart[(((long)(p * 64 + b)) * 8 + r) * 256 + t];
    xl[r * 256 + t] = (pp + 1e-8f * svs) * rs[r * 4 + hcol];
    hl[r * 256 + t] = slots[b * 2048 + r * 256 + t];
  }
  __syncthreads();
  const int gate = t >> 6;   // 0..3 (3 idle)
  const int c = t & 63;
  if (gate < 3) {
    const int gcol = gate * 256 + s * 64 + c;
    float ai[8] = {}, ah[8] = {};
    for (int k = 0; k < 256; k += 4) {
      float w_i[4], w_h[4];
#pragma unroll
      for (int u = 0; u < 4; ++u) {
        w_i[u] = wihT[(k + u) * 768 + gcol];
        w_h[u] = whhT[(k + u) * 768 + gcol];
      }
#pragma unroll
      for (int r = 0; r < 8; ++r) {
        const float4 x4 = *(const float4*)(xl + r * 256 + k);
        const float4 h4 = *(const float4*)(hl + r * 256 + k);
        ai[r] += x4.x * w_i[0] + x4.y * w_i[1] + x4.z * w_i[2] + x4.w * w_i[3];
        ah[r] += h4.x * w_h[0] + h4.y * w_h[1] + h4.z * w_h[2] + h4.w * w_h[3];
      }
    }
    const float bi = bih[gcol], bh = bhh[gcol];
#pragma unroll
    for (int r = 0; r < 8; ++r) {
      gbuf[gate * 1024 + r * 64 + c] = ai[r] + bi;
      gbuf[gate * 1024 + 512 + r * 64 + c] = ah[r] + bh;
    }
  }
  __syncthreads();
#pragma unroll
  for (int o = 0; o < 2; ++o) {
    const int idx = o * 256 + t;
    const int r = idx >> 6, cc = idx & 63;
    const float gi_r = gbuf[r * 64 + cc], gh_r = gbuf[512 + r * 64 + cc];
    const float gi_z = gbuf[1024 + r * 64 + cc], gh_z = gbuf[1536 + r * 64 + cc];
    const float gi_n = gbuf[2048 + r * 64 + cc], gh_n = gbuf[2560 + r * 64 + cc];
    const float rr = 1.f / (1.f + __expf(-(gi_r + gh_r)));
    const float zz = 1.f / (1.f + __expf(-(gi_z + gh_z)));
    const float nn = tanhf(gi_n + rr * gh_n);
    const float h_old = hl[r * 256 + s * 64 + cc];
    const float hn = (1.f - zz) * nn + zz * h_old;
    slots[b * 2048 + r * 256 + s * 64 + cc] = hn;
    if (LAST) dout[b * 2048 + r * 256 + s * 64 + cc] = hn;
  }
}

// ---------------------------------------------------------------------------
extern "C" void kernel_launch(void* const* d_in, const int* in_sizes, int n_in,
                              void* d_out, int out_size, void* d_ws,
                              size_t ws_size, hipStream_t stream) {
  const float* xin = (const float*)d_in[0];
  const float* cond = (const float*)d_in[1];
  const float* lnin_w = (const float*)d_in[2];
  const float* lnin_b = (const float*)d_in[3];
  const float* lns_w = (const float*)d_in[4];
  const float* lns_b = (const float*)d_in[5];
  const float* wq = (const float*)d_in[6];
  const float* wk = (const float*)d_in[7];
  const float* wv = (const float*)d_in[8];
  const float* gwih = (const float*)d_in[9];
  const float* gwhh = (const float*)d_in[10];
  const float* gbih = (const float*)d_in[11];
  const float* gbhh = (const float*)d_in[12];
  float* out = (float*)d_out;

  char* ws = (char*)d_ws;
  unsigned short* Kb = (unsigned short*)ws;  ws += 64l * 4096 * 256 * 2;   // 128MB
  unsigned short* Vt = (unsigned short*)ws;  ws += 64l * 256 * 4096 * 2;   // 128MB
  unsigned short* Wp = (unsigned short*)ws;  ws += 512l * 256 * 2;
  float* c12 = (float*)ws;                   ws += 1024l * 4;
  float* upart = (float*)ws;                 ws += 16l * 64 * 8 * 256 * 4; // 8MB
  float* svpart = (float*)ws;                ws += 16l * 64 * 256 * 4;     // 1MB
  float* rowsum_part = (float*)ws;           ws += 16l * 64 * 32 * 4;
  float* qbuf = (float*)ws;                  ws += 512l * 256 * 4;
  float* slots = (float*)ws;                 ws += 512l * 256 * 4;
  float* wihT = (float*)ws;                  ws += 256l * 768 * 4;
  float* whhT = (float*)ws;                  ws += 256l * 768 * 4;
  float* wqT = (float*)ws;                   ws += 256l * 256 * 4;
  // total ~268 MB

  hipMemcpyAsync(slots, cond, 512 * 256 * 4, hipMemcpyDeviceToDevice, stream);
  k_wprep<<<128, 256, 0, stream>>>(wk, wv, lnin_w, lnin_b, Wp, c12);
  k_transpose<<<1792, 256, 0, stream>>>(gwih, gwhh, wq, wihT, whhT, wqT);
  k_gemm<<<8192, 256, 0, stream>>>(xin, Wp, c12, Kb, Vt);

  for (int it = 0; it < 3; ++it) {
    k_q<<<64, 256, 0, stream>>>(slots, lns_w, lns_b, wqT, qbuf);
    if (it == 2)
      k_att<true><<<dim3(16, 64), 256, 0, stream>>>(
          qbuf, Kb, Vt, upart, svpart, rowsum_part, out + 131072);
    else
      k_att<false><<<dim3(16, 64), 256, 0, stream>>>(
          qbuf, Kb, Vt, upart, svpart, rowsum_part, out + 131072);
    if (it == 2)
      k_gru<true><<<dim3(4, 64), 256, 0, stream>>>(upart, svpart, rowsum_part,
                                                   wihT, whhT, gbih, gbhh, slots, out);
    else
      k_gru<false><<<dim3(4, 64), 256, 0, stream>>>(upart, svpart, rowsum_part,
                                                    wihT, whhT, gbih, gbhh, slots, out);
  }
}

// Round 4
// 786.268 us; speedup vs baseline: 1.3950x; 1.3950x over previous
//
#include <hip/hip_runtime.h>
#include <hip/hip_bf16.h>
#include <math.h>

// SlotAttention: B=64 N=4096 F=256 D=256 KVQ=256 H=4 S=8 DH=64 ITERS=3
// Round 4: back to LDS-staged MFMA GEMM (r2 structure) + T2 XOR swizzle on
// both operands (A: swizzled ds_write; B: pre-swizzled global_load_lds source)
// + LN stats fused into A staging. MFMA attention kept from r3 (sv only in
// iter 0). GRU fused with next-iter LN+q projection.

using frag_ab = __attribute__((ext_vector_type(8))) short;   // 8 bf16
using f32x4  = __attribute__((ext_vector_type(4))) float;

__device__ __forceinline__ unsigned short f2bf(float f) {
  unsigned int x = __float_as_uint(f);
  x += 0x7fffu + ((x >> 16) & 1u);   // RNE
  return (unsigned short)(x >> 16);
}
__device__ __forceinline__ float bf2f(unsigned short u) {
  return __uint_as_float((unsigned int)u << 16);
}

// ---------------------------------------------------------------------------
// Weight prep: Wp[n][k] = bf16(W[n][k]*lnw[k]); c12[n]=sum(b*W), c12[512+n]=sum(w*W)
__global__ __launch_bounds__(256) void k_wprep(
    const float* __restrict__ wk, const float* __restrict__ wv,
    const float* __restrict__ lnw, const float* __restrict__ lnb,
    unsigned short* __restrict__ Wp, float* __restrict__ c12) {
  const int lane = threadIdx.x & 63;
  const int n = blockIdx.x * 4 + (threadIdx.x >> 6);
  const float* W = (n < 256) ? (wk + n * 256) : (wv + (long)(n - 256) * 256);
  const float4 w4 = *(const float4*)(W + lane * 4);
  const float4 g4 = *(const float4*)(lnw + lane * 4);
  const float4 b4 = *(const float4*)(lnb + lane * 4);
  float c1 = w4.x * b4.x + w4.y * b4.y + w4.z * b4.z + w4.w * b4.w;
  float c2 = w4.x * g4.x + w4.y * g4.y + w4.z * g4.z + w4.w * g4.w;
  uint2 o;
  o.x = (unsigned)f2bf(w4.x * g4.x) | ((unsigned)f2bf(w4.y * g4.y) << 16);
  o.y = (unsigned)f2bf(w4.z * g4.z) | ((unsigned)f2bf(w4.w * g4.w) << 16);
  *(uint2*)(Wp + n * 256 + lane * 4) = o;
#pragma unroll
  for (int m = 1; m < 64; m <<= 1) {
    c1 += __shfl_xor(c1, m);
    c2 += __shfl_xor(c2, m);
  }
  if (lane == 0) {
    c12[n] = c1;
    c12[512 + n] = c2;
  }
}

// ---------------------------------------------------------------------------
__global__ void k_transpose(const float* __restrict__ wih,
                            const float* __restrict__ whh,
                            const float* __restrict__ wqs,
                            float* __restrict__ wihT, float* __restrict__ whhT,
                            float* __restrict__ wqT) {
  const int idx = blockIdx.x * 256 + threadIdx.x;
  if (idx < 768 * 256) {
    const int g = idx >> 8, k = idx & 255;
    wihT[k * 768 + g] = wih[idx];
  } else if (idx < 2 * 768 * 256) {
    const int j = idx - 768 * 256;
    const int g = j >> 8, k = j & 255;
    whhT[k * 768 + g] = whh[j];
  } else {
    const int j = idx - 2 * 768 * 256;
    const int c = j >> 8, k = j & 255;
    wqT[k * 256 + c] = wqs[j];
  }
}

// ---------------------------------------------------------------------------
// Projection GEMM: BM=128 BN=128 BK=64, 4 waves (2x2). LN stats fused into A
// staging; epilogue affine; K rows -> Kb, V cols transposed -> Vt[b][d][j].
__global__ __launch_bounds__(256) void k_gemm(
    const float* __restrict__ xin, const unsigned short* __restrict__ Wp,
    const float* __restrict__ c12, unsigned short* __restrict__ Kb,
    unsigned short* __restrict__ Vt) {
  __shared__ __align__(16) char sh[32768];   // As 16K | Bs 16K; reused for repack
  __shared__ float2 stats_s[128];
  unsigned short* As = (unsigned short*)sh;
  unsigned short* Bs = (unsigned short*)(sh + 16384);
  const int t = threadIdx.x;
  const int id = blockIdx.x;
  const int work = (id & 7) * 1024 + (id >> 3);   // bijective XCD chunking
  const int mblk = work >> 2, nblk = work & 3;
  const long row0 = (long)mblk * 128;
  const int n0 = nblk * 128;
  const int lane = t & 63, w = t >> 6;
  const int wm = w >> 1, wn = w & 1;
  const int li = lane & 15, kg = lane >> 4;

  f32x4 acc[4][4];
#pragma unroll
  for (int m = 0; m < 4; ++m)
#pragma unroll
    for (int n = 0; n < 4; ++n) acc[m][n] = (f32x4){0.f, 0.f, 0.f, 0.f};

  float sacc[4] = {0.f, 0.f, 0.f, 0.f};
  float ssacc[4] = {0.f, 0.f, 0.f, 0.f};

  for (int ks = 0; ks < 4; ++ks) {
    if (ks) __syncthreads();
    // A: fp32 -> bf16, swizzled ds_write; stats accumulated in-flight.
#pragma unroll
    for (int rnd = 0; rnd < 4; ++rnd) {
      const int o = rnd * 4096 + t * 16;     // byte offset in bf16 tile
      const int r = o >> 7;                  // = rnd*32 + (t>>3)
      const int kb = o & 127;                // byte col (16B per thread)
      const float4* src =
          (const float4*)((const char*)xin + (row0 + r) * 1024 + ks * 256 + kb * 2);
      const float4 x0 = src[0];
      const float4 x1 = src[1];
      sacc[rnd] += x0.x + x0.y + x0.z + x0.w + x1.x + x1.y + x1.z + x1.w;
      ssacc[rnd] += x0.x * x0.x + x0.y * x0.y + x0.z * x0.z + x0.w * x0.w +
                    x1.x * x1.x + x1.y * x1.y + x1.z * x1.z + x1.w * x1.w;
      uint4 p;
      p.x = (unsigned)f2bf(x0.x) | ((unsigned)f2bf(x0.y) << 16);
      p.y = (unsigned)f2bf(x0.z) | ((unsigned)f2bf(x0.w) << 16);
      p.z = (unsigned)f2bf(x1.x) | ((unsigned)f2bf(x1.y) << 16);
      p.w = (unsigned)f2bf(x1.z) | ((unsigned)f2bf(x1.w) << 16);
      *(uint4*)((char*)As + (r * 128 + (kb ^ ((r & 7) << 4)))) = p;
    }
    // B: global_load_lds, source pre-swizzled so linear LDS dest = swizzled tile
#pragma unroll
    for (int rnd = 0; rnd < 4; ++rnd) {
      const int o = rnd * 4096 + t * 16;
      const int r = o >> 7, kb = o & 127;
      const int kbx = kb ^ ((r & 7) << 4);
      __builtin_amdgcn_global_load_lds(
          (const unsigned int*)((const char*)Wp + (long)(n0 + r) * 512 + ks * 128 + kbx),
          (unsigned int*)((char*)Bs + o), 16, 0, 0);
    }
    __syncthreads();
#pragma unroll
    for (int kk = 0; kk < 2; ++kk) {
      frag_ab af[4], bf[4];
#pragma unroll
      for (int m = 0; m < 4; ++m) {
        const int ra = wm * 64 + m * 16 + li;
        const int cb = kk * 64 + kg * 16;
        af[m] = *(const frag_ab*)((const char*)As +
                                  (ra * 128 + (cb ^ ((ra & 7) << 4))));
      }
#pragma unroll
      for (int n = 0; n < 4; ++n) {
        const int rb = wn * 64 + n * 16 + li;
        const int cb = kk * 64 + kg * 16;
        bf[n] = *(const frag_ab*)((const char*)Bs +
                                  (rb * 128 + (cb ^ ((rb & 7) << 4))));
      }
#pragma unroll
      for (int m = 0; m < 4; ++m)
#pragma unroll
        for (int n = 0; n < 4; ++n)
          acc[m][n] =
              __builtin_amdgcn_mfma_f32_16x16x32_bf16(af[m], bf[n], acc[m][n], 0, 0, 0);
    }
  }
  // finalize stats: reduce over the 8 threads (t&7) covering each row
#pragma unroll
  for (int rnd = 0; rnd < 4; ++rnd) {
    float s = sacc[rnd], ss = ssacc[rnd];
    s += __shfl_xor(s, 1); s += __shfl_xor(s, 2); s += __shfl_xor(s, 4);
    ss += __shfl_xor(ss, 1); ss += __shfl_xor(ss, 2); ss += __shfl_xor(ss, 4);
    const float mn = s * (1.f / 256.f);
    const float rstd = rsqrtf(ss * (1.f / 256.f) - mn * mn + 1e-5f);
    if ((t & 7) == 0) stats_s[rnd * 32 + (t >> 3)] = make_float2(mn, rstd);
  }
  __syncthreads();   // stats visible; MFMA LDS reads drained before repack

  if (nblk < 2) {
    // K half: repack [128 r][128 c] bf16 (row-quarter XOR) then coalesced store
    unsigned short* Krep = (unsigned short*)sh;
#pragma unroll
    for (int m = 0; m < 4; ++m)
#pragma unroll
      for (int n = 0; n < 4; ++n) {
        const int C = wn * 64 + n * 16 + li;
        const int gn = n0 + C;
        const float c1v = c12[gn];
        const float c2v = c12[512 + gn];
#pragma unroll
        for (int r = 0; r < 4; ++r) {
          const int R = wm * 64 + m * 16 + kg * 4 + r;
          const float2 ms = stats_s[R];
          const float val = ms.y * acc[m][n][r] + (c1v - ms.x * ms.y * c2v);
          const int off = (R * 256 + C * 2) ^ (((R >> 2) & 3) << 5);
          *(unsigned short*)((char*)Krep + off) = f2bf(val);
        }
      }
    __syncthreads();
#pragma unroll
    for (int p = 0; p < 8; ++p) {
      const int idx = p * 256 + t;
      const int R = idx >> 4, c = (idx & 15) * 16;
      const uint4 v =
          *(const uint4*)((char*)Krep + ((R * 256 + c) ^ (((R >> 2) & 3) << 5)));
      *(uint4*)(Kb + (row0 + R) * 256 + nblk * 128 + c / 2) = v;
    }
  } else {
    // V half: transpose-repack [128 d][128 j] bf16 (d XOR swizzle), store Vt
    unsigned short* Vrep = (unsigned short*)sh;
#pragma unroll
    for (int m = 0; m < 4; ++m)
#pragma unroll
      for (int n = 0; n < 4; ++n) {
        const int dl = wn * 64 + n * 16 + li;
        const int gn = n0 + dl;
        const float c1v = c12[gn];
        const float c2v = c12[512 + gn];
#pragma unroll
        for (int r = 0; r < 4; ++r) {
          const int R = wm * 64 + m * 16 + kg * 4 + r;   // j within tile
          const float2 ms = stats_s[R];
          const float val = ms.y * acc[m][n][r] + (c1v - ms.x * ms.y * c2v);
          const int off = dl * 256 + ((R * 2) ^ ((dl & 7) << 4));
          *(unsigned short*)((char*)Vrep + off) = f2bf(val);
        }
      }
    __syncthreads();
    const long b = row0 >> 12;
    const long jb = row0 & 4095;
#pragma unroll
    for (int p = 0; p < 8; ++p) {
      const int idx = p * 256 + t;
      const int dl = idx >> 4, c16 = idx & 15;
      const uint4 v = *(const uint4*)((char*)Vrep + dl * 256 +
                                      ((c16 * 16) ^ ((dl & 7) << 4)));
      const int dglob = (nblk - 2) * 128 + dl;
      *(uint4*)(Vt + ((long)(b * 256 + dglob)) * 4096 + jb + c16 * 8) = v;
    }
  }
}

// ---------------------------------------------------------------------------
// LN(slots) + q = sn @ wq^T. One block per b (initial q only).
__global__ __launch_bounds__(256) void k_q(
    const float* __restrict__ slots, const float* __restrict__ lnw,
    const float* __restrict__ lnb, const float* __restrict__ wqT,
    float* __restrict__ qout) {
  __shared__ float sl[8 * 256];
  __shared__ float mstat[8], rstat[8];
  const int b = blockIdx.x, t = threadIdx.x;
#pragma unroll
  for (int i = 0; i < 8; ++i) sl[i * 256 + t] = slots[b * 2048 + i * 256 + t];
  __syncthreads();
  if (t < 8) {
    float s = 0.f, ss = 0.f;
    for (int k = 0; k < 256; ++k) {
      const float x = sl[t * 256 + k];
      s += x;
      ss += x * x;
    }
    const float m = s * (1.f / 256.f);
    mstat[t] = m;
    rstat[t] = rsqrtf(ss * (1.f / 256.f) - m * m + 1e-5f);
  }
  __syncthreads();
  const float w = lnw[t], bb = lnb[t];
#pragma unroll
  for (int i = 0; i < 8; ++i)
    sl[i * 256 + t] = (sl[i * 256 + t] - mstat[i]) * rstat[i] * w + bb;
  __syncthreads();
  float acc[8] = {};
  for (int k = 0; k < 256; k += 4) {
    const float w0 = wqT[(k + 0) * 256 + t];
    const float w1 = wqT[(k + 1) * 256 + t];
    const float w2 = wqT[(k + 2) * 256 + t];
    const float w3 = wqT[(k + 3) * 256 + t];
#pragma unroll
    for (int i = 0; i < 8; ++i) {
      const float4 x4 = *(const float4*)(sl + i * 256 + k);
      acc[i] += x4.x * w0 + x4.y * w1 + x4.z * w2 + x4.w * w3;
    }
  }
#pragma unroll
  for (int i = 0; i < 8; ++i) qout[b * 2048 + i * 256 + t] = acc[i];
}

// ---------------------------------------------------------------------------
// MFMA attention (r3): block (jt,b), 8 chunks of 32 j. Wave = head.
// FIRST: also accumulate sum_j V (iteration-invariant).
template <bool LAST, bool FIRST>
__global__ __launch_bounds__(256) void k_att(
    const float* __restrict__ qin, const unsigned short* __restrict__ Kb,
    const unsigned short* __restrict__ Vt, float* __restrict__ upart,
    float* __restrict__ svpart, float* __restrict__ rowsum_part,
    float* __restrict__ attn_out) {
  __shared__ float dsm[32 * 33];
  __shared__ float wred[4 * 32];
  const int t = threadIdx.x;
  const int lane = t & 63;
  const int h = t >> 6;
  const int jt = blockIdx.x;
  const int b = blockIdx.y;
  const long j0 = (long)jt * 256;
  const int li = lane & 15;
  const int kg = lane >> 4;
  const bool ival = li < 8;

  frag_ab qf[2];
#pragma unroll
  for (int ksub = 0; ksub < 2; ++ksub) {
    union { frag_ab f; unsigned short u[8]; } tq;
#pragma unroll
    for (int e = 0; e < 8; ++e)
      tq.u[e] = ival ? f2bf(qin[b * 2048 + li * 256 + h * 64 + ksub * 32 + kg * 8 + e])
                     : (unsigned short)0;
    qf[ksub] = tq.f;
  }

  const int sc = t >> 3, sp = t & 7;
  float rs0 = 0, rs1 = 0, rs2 = 0, rs3 = 0;
  f32x4 pv[4];
#pragma unroll
  for (int d = 0; d < 4; ++d) pv[d] = (f32x4){0.f, 0.f, 0.f, 0.f};
  float sv[4] = {0.f, 0.f, 0.f, 0.f};

  for (int ch = 0; ch < 8; ++ch) {
    const long jc = j0 + ch * 32;
    f32x4 dacc[2];
    dacc[0] = (f32x4){0.f, 0.f, 0.f, 0.f};
    dacc[1] = (f32x4){0.f, 0.f, 0.f, 0.f};
#pragma unroll
    for (int jsub = 0; jsub < 2; ++jsub)
#pragma unroll
      for (int ksub = 0; ksub < 2; ++ksub) {
        const frag_ab af =
            *(const frag_ab*)(Kb + ((long)b * 4096 + jc + jsub * 16 + li) * 256 +
                              h * 64 + ksub * 32 + kg * 8);
        dacc[jsub] = __builtin_amdgcn_mfma_f32_16x16x32_bf16(af, qf[ksub], dacc[jsub], 0, 0, 0);
      }
    __syncthreads();
    if (ival) {
#pragma unroll
      for (int jsub = 0; jsub < 2; ++jsub)
#pragma unroll
        for (int r = 0; r < 4; ++r)
          dsm[(jsub * 16 + kg * 4 + r) * 33 + li * 4 + h] = dacc[jsub][r] * 0.125f;
    }
    __syncthreads();
    {
      float v0 = dsm[sc * 33 + sp * 4 + 0];
      float v1 = dsm[sc * 33 + sp * 4 + 1];
      float v2 = dsm[sc * 33 + sp * 4 + 2];
      float v3 = dsm[sc * 33 + sp * 4 + 3];
      float mx = fmaxf(fmaxf(v0, v1), fmaxf(v2, v3));
      mx = fmaxf(mx, __shfl_xor(mx, 1));
      mx = fmaxf(mx, __shfl_xor(mx, 2));
      mx = fmaxf(mx, __shfl_xor(mx, 4));
      v0 = __expf(v0 - mx); v1 = __expf(v1 - mx);
      v2 = __expf(v2 - mx); v3 = __expf(v3 - mx);
      float sum = v0 + v1 + v2 + v3;
      sum += __shfl_xor(sum, 1);
      sum += __shfl_xor(sum, 2);
      sum += __shfl_xor(sum, 4);
      const float inv = 1.f / sum;
      v0 *= inv; v1 *= inv; v2 *= inv; v3 *= inv;
      dsm[sc * 33 + sp * 4 + 0] = v0;
      dsm[sc * 33 + sp * 4 + 1] = v1;
      dsm[sc * 33 + sp * 4 + 2] = v2;
      dsm[sc * 33 + sp * 4 + 3] = v3;
      rs0 += v0; rs1 += v1; rs2 += v2; rs3 += v3;
      if (LAST)
        attn_out[((long)(b * 8 + sp)) * 4096 + jc + sc] =
            (v0 + v1 + v2 + v3) * 0.25f;
    }
    __syncthreads();
    frag_ab pa;
    {
      union { frag_ab f; unsigned short u[8]; } tp;
#pragma unroll
      for (int e = 0; e < 8; ++e)
        tp.u[e] = ival ? f2bf(dsm[(kg * 8 + e) * 33 + li * 4 + h]) : (unsigned short)0;
      pa = tp.f;
    }
#pragma unroll
    for (int dt = 0; dt < 4; ++dt) {
      const frag_ab vf =
          *(const frag_ab*)(Vt + ((long)b * 256 + h * 64 + dt * 16 + li) * 4096 +
                            jc + kg * 8);
      pv[dt] = __builtin_amdgcn_mfma_f32_16x16x32_bf16(pa, vf, pv[dt], 0, 0, 0);
      if (FIRST) {
        const unsigned short* vu = (const unsigned short*)&vf;
        float svl = 0.f;
#pragma unroll
        for (int e = 0; e < 8; ++e) svl += bf2f(vu[e]);
        sv[dt] += svl;
      }
    }
  }
  if (kg < 2) {
#pragma unroll
    for (int dt = 0; dt < 4; ++dt)
#pragma unroll
      for (int r = 0; r < 4; ++r)
        upart[(((long)(jt * 64 + b)) * 8 + kg * 4 + r) * 256 + h * 64 + dt * 16 + li] =
            pv[dt][r];
  }
  if (FIRST) {
#pragma unroll
    for (int dt = 0; dt < 4; ++dt) {
      sv[dt] += __shfl_xor(sv[dt], 16);
      sv[dt] += __shfl_xor(sv[dt], 32);
    }
    if (kg == 0) {
#pragma unroll
      for (int dt = 0; dt < 4; ++dt)
        svpart[((long)(jt * 64 + b)) * 256 + h * 64 + dt * 16 + li] = sv[dt];
    }
  }
  rs0 += __shfl_xor(rs0, 8); rs0 += __shfl_xor(rs0, 16); rs0 += __shfl_xor(rs0, 32);
  rs1 += __shfl_xor(rs1, 8); rs1 += __shfl_xor(rs1, 16); rs1 += __shfl_xor(rs1, 32);
  rs2 += __shfl_xor(rs2, 8); rs2 += __shfl_xor(rs2, 16); rs2 += __shfl_xor(rs2, 32);
  rs3 += __shfl_xor(rs3, 8); rs3 += __shfl_xor(rs3, 16); rs3 += __shfl_xor(rs3, 32);
  if ((t & 63) < 8) {
    float* wr = wred + (t >> 6) * 32 + sp * 4;
    wr[0] = rs0; wr[1] = rs1; wr[2] = rs2; wr[3] = rs3;
  }
  __syncthreads();
  if (t < 32)
    rowsum_part[((long)(jt * 64 + b)) * 32 + t] =
        wred[t] + wred[32 + t] + wred[64 + t] + wred[96 + t];
}

// ---------------------------------------------------------------------------
// GRU cell fused with next-iteration LN + q projection. One block per b.
template <bool LAST>
__global__ __launch_bounds__(256) void k_gruq(
    const float* __restrict__ upart, const float* __restrict__ svpart,
    const float* __restrict__ rowsum_part, const float* __restrict__ wihT,
    const float* __restrict__ whhT, const float* __restrict__ bih,
    const float* __restrict__ bhh, const float* __restrict__ lnw,
    const float* __restrict__ lnb, const float* __restrict__ wqT,
    float* __restrict__ slots, float* __restrict__ qout,
    float* __restrict__ dout) {
  __shared__ float xl[8 * 256];
  __shared__ float hl[8 * 256];
  __shared__ float rs[32];
  __shared__ float mstat[8], rstat[8];
  const int t = threadIdx.x;
  const int b = blockIdx.x;
  if (t < 32) {
    float s2 = 0.f;
#pragma unroll
    for (int p = 0; p < 16; ++p) s2 += rowsum_part[((long)(p * 64 + b)) * 32 + t];
    rs[t] = 1.f / (s2 + 4096.f * 1e-8f);
  }
  float svs = 0.f;
#pragma unroll
  for (int p = 0; p < 16; ++p) svs += svpart[((long)(p * 64 + b)) * 256 + t];
  __syncthreads();
  const int hcol = t >> 6;
#pragma unroll
  for (int r = 0; r < 8; ++r) {
    float pp = 0.f;
#pragma unroll
    for (int p = 0; p < 16; ++p)
      pp += upart[(((long)(p * 64 + b)) * 8 + r) * 256 + t];
    xl[r * 256 + t] = (pp + 1e-8f * svs) * rs[r * 4 + hcol];
    hl[r * 256 + t] = slots[b * 2048 + r * 256 + t];
  }
  __syncthreads();
  float air[8] = {}, aiz[8] = {}, ain[8] = {};
  float ahr[8] = {}, ahz[8] = {}, ahn[8] = {};
  for (int k = 0; k < 256; k += 4) {
    float wir[4], wiz[4], win_[4], whr[4], whz[4], whn[4];
#pragma unroll
    for (int u = 0; u < 4; ++u) {
      wir[u] = wihT[(k + u) * 768 + t];
      wiz[u] = wihT[(k + u) * 768 + 256 + t];
      win_[u] = wihT[(k + u) * 768 + 512 + t];
      whr[u] = whhT[(k + u) * 768 + t];
      whz[u] = whhT[(k + u) * 768 + 256 + t];
      whn[u] = whhT[(k + u) * 768 + 512 + t];
    }
#pragma unroll
    for (int r = 0; r < 8; ++r) {
      const float4 x4 = *(const float4*)(xl + r * 256 + k);
      const float4 h4 = *(const float4*)(hl + r * 256 + k);
      air[r] += x4.x * wir[0] + x4.y * wir[1] + x4.z * wir[2] + x4.w * wir[3];
      aiz[r] += x4.x * wiz[0] + x4.y * wiz[1] + x4.z * wiz[2] + x4.w * wiz[3];
      ain[r] += x4.x * win_[0] + x4.y * win_[1] + x4.z * win_[2] + x4.w * win_[3];
      ahr[r] += h4.x * whr[0] + h4.y * whr[1] + h4.z * whr[2] + h4.w * whr[3];
      ahz[r] += h4.x * whz[0] + h4.y * whz[1] + h4.z * whz[2] + h4.w * whz[3];
      ahn[r] += h4.x * whn[0] + h4.y * whn[1] + h4.z * whn[2] + h4.w * whn[3];
    }
  }
  const float bir = bih[t], biz = bih[256 + t], bin_ = bih[512 + t];
  const float bhr = bhh[t], bhz = bhh[256 + t], bhn = bhh[512 + t];
  float hn[8];
#pragma unroll
  for (int r = 0; r < 8; ++r) {
    const float rr = 1.f / (1.f + __expf(-(air[r] + bir + ahr[r] + bhr)));
    const float zz = 1.f / (1.f + __expf(-(aiz[r] + biz + ahz[r] + bhz)));
    const float nn2 = tanhf(ain[r] + bin_ + rr * (ahn[r] + bhn));
    hn[r] = (1.f - zz) * nn2 + zz * hl[r * 256 + t];
    slots[b * 2048 + r * 256 + t] = hn[r];
    if (LAST) dout[b * 2048 + r * 256 + t] = hn[r];
  }
  if (LAST) return;
  // ---- fused LN + q for the next iteration ----
  __syncthreads();   // all xl/hl readers done
#pragma unroll
  for (int r = 0; r < 8; ++r) xl[r * 256 + t] = hn[r];
  __syncthreads();
  if (t < 8) {
    float s = 0.f, ss = 0.f;
    for (int k = 0; k < 256; ++k) {
      const float x = xl[t * 256 + k];
      s += x;
      ss += x * x;
    }
    const float m = s * (1.f / 256.f);
    mstat[t] = m;
    rstat[t] = rsqrtf(ss * (1.f / 256.f) - m * m + 1e-5f);
  }
  __syncthreads();
  const float w = lnw[t], bb = lnb[t];
#pragma unroll
  for (int i = 0; i < 8; ++i)
    xl[i * 256 + t] = (xl[i * 256 + t] - mstat[i]) * rstat[i] * w + bb;
  __syncthreads();
  float acq[8] = {};
  for (int k = 0; k < 256; k += 4) {
    const float w0 = wqT[(k + 0) * 256 + t];
    const float w1 = wqT[(k + 1) * 256 + t];
    const float w2 = wqT[(k + 2) * 256 + t];
    const float w3 = wqT[(k + 3) * 256 + t];
#pragma unroll
    for (int i = 0; i < 8; ++i) {
      const float4 x4 = *(const float4*)(xl + i * 256 + k);
      acq[i] += x4.x * w0 + x4.y * w1 + x4.z * w2 + x4.w * w3;
    }
  }
#pragma unroll
  for (int i = 0; i < 8; ++i) qout[b * 2048 + i * 256 + t] = acq[i];
}

// ---------------------------------------------------------------------------
extern "C" void kernel_launch(void* const* d_in, const int* in_sizes, int n_in,
                              void* d_out, int out_size, void* d_ws,
                              size_t ws_size, hipStream_t stream) {
  const float* xin = (const float*)d_in[0];
  const float* cond = (const float*)d_in[1];
  const float* lnin_w = (const float*)d_in[2];
  const float* lnin_b = (const float*)d_in[3];
  const float* lns_w = (const float*)d_in[4];
  const float* lns_b = (const float*)d_in[5];
  const float* wq = (const float*)d_in[6];
  const float* wk = (const float*)d_in[7];
  const float* wv = (const float*)d_in[8];
  const float* gwih = (const float*)d_in[9];
  const float* gwhh = (const float*)d_in[10];
  const float* gbih = (const float*)d_in[11];
  const float* gbhh = (const float*)d_in[12];
  float* out = (float*)d_out;

  char* ws = (char*)d_ws;
  unsigned short* Kb = (unsigned short*)ws;  ws += 64l * 4096 * 256 * 2;   // 128MB
  unsigned short* Vt = (unsigned short*)ws;  ws += 64l * 256 * 4096 * 2;   // 128MB
  unsigned short* Wp = (unsigned short*)ws;  ws += 512l * 256 * 2;
  float* c12 = (float*)ws;                   ws += 1024l * 4;
  float* upart = (float*)ws;                 ws += 16l * 64 * 8 * 256 * 4; // 8MB
  float* svpart = (float*)ws;                ws += 16l * 64 * 256 * 4;     // 1MB
  float* rowsum_part = (float*)ws;           ws += 16l * 64 * 32 * 4;
  float* qbuf = (float*)ws;                  ws += 512l * 256 * 4;
  float* slots = (float*)ws;                 ws += 512l * 256 * 4;
  float* wihT = (float*)ws;                  ws += 256l * 768 * 4;
  float* whhT = (float*)ws;                  ws += 256l * 768 * 4;
  float* wqT = (float*)ws;                   ws += 256l * 256 * 4;
  // total ~268 MB

  hipMemcpyAsync(slots, cond, 512 * 256 * 4, hipMemcpyDeviceToDevice, stream);
  k_wprep<<<128, 256, 0, stream>>>(wk, wv, lnin_w, lnin_b, Wp, c12);
  k_transpose<<<1792, 256, 0, stream>>>(gwih, gwhh, wq, wihT, whhT, wqT);
  k_gemm<<<8192, 256, 0, stream>>>(xin, Wp, c12, Kb, Vt);
  k_q<<<64, 256, 0, stream>>>(slots, lns_w, lns_b, wqT, qbuf);

  // iter 0
  k_att<false, true><<<dim3(16, 64), 256, 0, stream>>>(
      qbuf, Kb, Vt, upart, svpart, rowsum_part, out + 131072);
  k_gruq<false><<<64, 256, 0, stream>>>(upart, svpart, rowsum_part, wihT, whhT,
                                        gbih, gbhh, lns_w, lns_b, wqT, slots,
                                        qbuf, out);
  // iter 1
  k_att<false, false><<<dim3(16, 64), 256, 0, stream>>>(
      qbuf, Kb, Vt, upart, svpart, rowsum_part, out + 131072);
  k_gruq<false><<<64, 256, 0, stream>>>(upart, svpart, rowsum_part, wihT, whhT,
                                        gbih, gbhh, lns_w, lns_b, wqT, slots,
                                        qbuf, out);
  // iter 2
  k_att<true, false><<<dim3(16, 64), 256, 0, stream>>>(
      qbuf, Kb, Vt, upart, svpart, rowsum_part, out + 131072);
  k_gruq<true><<<64, 256, 0, stream>>>(upart, svpart, rowsum_part, wihT, whhT,
                                       gbih, gbhh, lns_w, lns_b, wqT, slots,
                                       qbuf, out);
}